// Round 1
// baseline (1532.296 us; speedup 1.0000x reference)
//
#include <hip/hip_runtime.h>
#include <hip/hip_bf16.h>
#include <math.h>

using bf16 = __hip_bfloat16;

typedef __attribute__((ext_vector_type(8))) short short8;   // 8 bf16 (4 VGPR)
typedef __attribute__((ext_vector_type(4))) float f32x4;
typedef __attribute__((ext_vector_type(2))) unsigned int uint2v;

static constexpr int Bsz = 512, Nn = 8192, Dd = 4096, Hh = 2048;

// ---------------------------------------------------------------------------
// NT GEMM: C[M,N] = A[M,K] @ Bt[N,K]^T   (bf16 in, f32 accum)
// 128x128 tile, BK=64, 4 waves (2x2 of 64x64), mfma_f32_16x16x32_bf16.
// LDS tiles stored with chunk-level XOR swizzle: chunk (r,c) at slot (r, c^(r&7)).
// ---------------------------------------------------------------------------
enum { EPI_BF16 = 0, EPI_SCALE_F32, EPI_ENH, EPI_GELU_BIAS, EPI_BIAS_BF16, EPI_BIAS_F32 };

template<int EPI>
__global__ __launch_bounds__(256)
void gemm_nt(const bf16* __restrict__ A, const bf16* __restrict__ Bt,
             void* __restrict__ Cp, const bf16* __restrict__ sel,
             const float* __restrict__ bias, float scale,
             int M, int N, int K)
{
  __shared__ bf16 As[128 * 64];
  __shared__ bf16 Bs[128 * 64];
  const int tid  = threadIdx.x;
  const int lane = tid & 63;
  const int wave = tid >> 6;
  const int wm = wave >> 1, wn = wave & 1;
  const long brow = (long)blockIdx.y * 128;
  const long bcol = (long)blockIdx.x * 128;

  f32x4 acc[4][4] = {};

  for (int k0 = 0; k0 < K; k0 += 64) {
    __syncthreads();
#pragma unroll
    for (int i = 0; i < 4; ++i) {
      const int s  = i * 256 + tid;        // 16B chunk slot in [128][8] chunk grid
      const int r  = s >> 3;
      const int cs = s & 7;                // swizzled chunk col in LDS
      const int col = ((cs ^ (r & 7)) << 3);  // source k-col (involution)
      *reinterpret_cast<short8*>(&As[s << 3]) =
          *reinterpret_cast<const short8*>(&A[(brow + r) * K + k0 + col]);
      *reinterpret_cast<short8*>(&Bs[s << 3]) =
          *reinterpret_cast<const short8*>(&Bt[(bcol + r) * K + k0 + col]);
    }
    __syncthreads();
#pragma unroll
    for (int kk = 0; kk < 2; ++kk) {
      short8 af[4], bq[4];
      const int cc = (kk << 2) + (lane >> 4);   // chunk col 0..7 (pre-swizzle)
#pragma unroll
      for (int m = 0; m < 4; ++m) {
        const int r = wm * 64 + m * 16 + (lane & 15);
        af[m] = *reinterpret_cast<const short8*>(&As[((r << 3) + (cc ^ (r & 7))) << 3]);
      }
#pragma unroll
      for (int n = 0; n < 4; ++n) {
        const int r = wn * 64 + n * 16 + (lane & 15);
        bq[n] = *reinterpret_cast<const short8*>(&Bs[((r << 3) + (cc ^ (r & 7))) << 3]);
      }
#pragma unroll
      for (int m = 0; m < 4; ++m)
#pragma unroll
        for (int n = 0; n < 4; ++n)
          acc[m][n] = __builtin_amdgcn_mfma_f32_16x16x32_bf16(af[m], bq[n], acc[m][n], 0, 0, 0);
    }
  }

  // epilogue: C row = (lane>>4)*4 + j, col = lane&15 within each 16x16 frag
#pragma unroll
  for (int m = 0; m < 4; ++m) {
    const long row0 = brow + wm * 64 + m * 16 + ((lane >> 4) << 2);
#pragma unroll
    for (int n = 0; n < 4; ++n) {
      const long col = bcol + wn * 64 + n * 16 + (lane & 15);
#pragma unroll
      for (int j = 0; j < 4; ++j) {
        const long idx = (row0 + j) * N + col;
        const float v = acc[m][n][j];
        if constexpr (EPI == EPI_BF16) {
          reinterpret_cast<bf16*>(Cp)[idx] = __float2bfloat16(v);
        } else if constexpr (EPI == EPI_SCALE_F32) {
          reinterpret_cast<float*>(Cp)[idx] = v * scale;
        } else if constexpr (EPI == EPI_ENH) {
          reinterpret_cast<bf16*>(Cp)[idx] =
              __float2bfloat16(__bfloat162float(sel[idx]) + 0.1f * v);
        } else if constexpr (EPI == EPI_GELU_BIAS) {
          const float t = v + bias[col];
          reinterpret_cast<bf16*>(Cp)[idx] =
              __float2bfloat16(0.5f * t * (1.0f + erff(t * 0.7071067811865475f)));
        } else if constexpr (EPI == EPI_BIAS_BF16) {
          reinterpret_cast<bf16*>(Cp)[idx] = __float2bfloat16(v + bias[col]);
        } else { // EPI_BIAS_F32
          reinterpret_cast<float*>(Cp)[idx] = v + bias[col];
        }
      }
    }
  }
}

// ---------------------------------------------------------------------------
// f32 -> bf16 convert (4 elems/thread, exact grids)
// ---------------------------------------------------------------------------
__global__ __launch_bounds__(256)
void k_convert_bf16(const float* __restrict__ in, bf16* __restrict__ out, long n4)
{
  const long i = (long)blockIdx.x * 256 + threadIdx.x;
  if (i >= n4) return;
  const f32x4 v = *reinterpret_cast<const f32x4*>(&in[i * 4]);
  bf16 o[4] __attribute__((aligned(8)));
#pragma unroll
  for (int j = 0; j < 4; ++j) o[j] = __float2bfloat16(v[j]);
  *reinterpret_cast<uint2v*>(&out[i * 4]) = *reinterpret_cast<uint2v*>(o);
}

// ---------------------------------------------------------------------------
// transpose + convert: in f32 [R][C] -> out bf16 [C][R]; R,C multiples of 64
// ---------------------------------------------------------------------------
__global__ __launch_bounds__(256)
void k_transpose_bf16(const float* __restrict__ in, bf16* __restrict__ out, int R, int C)
{
  __shared__ float t[64][65];
  const int bc = blockIdx.x << 6;
  const int br = blockIdx.y << 6;
  for (int i = threadIdx.x; i < 4096; i += 256) {
    const int r = i >> 6, c = i & 63;
    t[r][c] = in[(long)(br + r) * C + (bc + c)];
  }
  __syncthreads();
  for (int i = threadIdx.x; i < 4096; i += 256) {
    const int r = i >> 6, c = i & 63;
    out[(long)(bc + r) * R + (br + c)] = __float2bfloat16(t[c][r]);
  }
}

// ---------------------------------------------------------------------------
// row-gather + convert: dst[i][:] = bf16(src[map[i]][:])   (4 f32/thread)
// ---------------------------------------------------------------------------
__global__ __launch_bounds__(256)
void k_gather_bf16(const float* __restrict__ src, const int* __restrict__ map,
                   bf16* __restrict__ dst, int cols)
{
  const long i = (long)blockIdx.x * 256 + threadIdx.x;
  const int cpr = cols >> 2;
  const int row = (int)(i / cpr);
  const int c4  = (int)(i % cpr) << 2;
  const f32x4 v = *reinterpret_cast<const f32x4*>(&src[(long)map[row] * cols + c4]);
  bf16 o[4] __attribute__((aligned(8)));
#pragma unroll
  for (int j = 0; j < 4; ++j) o[j] = __float2bfloat16(v[j]);
  *reinterpret_cast<uint2v*>(&dst[(long)row * cols + c4]) = *reinterpret_cast<uint2v*>(o);
}

// ---------------------------------------------------------------------------
// per-row softmax stats + top-8 (value-desc, tie -> lower index, like lax.top_k)
// one block (256 thr) per row of scores [512][8192]
// ---------------------------------------------------------------------------
__global__ __launch_bounds__(256)
void k_softmax_topk(const float* __restrict__ scores, int* __restrict__ tki,
                    float* __restrict__ tkw)
{
  const int b = blockIdx.x;
  const float* row = scores + (long)b * Nn;
  const int tid = threadIdx.x;
  __shared__ float red[8];
  __shared__ float cv[2048];
  __shared__ int   ci[2048];

  // pass 1: row max
  float mx = -INFINITY;
  for (int i = tid; i < Nn; i += 256) mx = fmaxf(mx, row[i]);
#pragma unroll
  for (int o = 32; o; o >>= 1) mx = fmaxf(mx, __shfl_down(mx, o));
  if ((tid & 63) == 0) red[tid >> 6] = mx;
  __syncthreads();
  mx = fmaxf(fmaxf(red[0], red[1]), fmaxf(red[2], red[3]));

  // pass 2: expsum + per-thread sorted top-8
  float tv[8]; int ti[8];
#pragma unroll
  for (int j = 0; j < 8; ++j) { tv[j] = -INFINITY; ti[j] = 0x7fffffff; }
  float sum = 0.f;
  for (int i = tid; i < Nn; i += 256) {
    const float v = row[i];
    sum += expf(v - mx);
    if (v > tv[7]) {            // strict >: equal value keeps earlier (lower) index
      tv[7] = v; ti[7] = i;
#pragma unroll
      for (int j = 7; j > 0; --j) {
        const bool sw = (tv[j] > tv[j-1]) || (tv[j] == tv[j-1] && ti[j] < ti[j-1]);
        if (sw) {
          const float fv = tv[j]; tv[j] = tv[j-1]; tv[j-1] = fv;
          const int   iv = ti[j]; ti[j] = ti[j-1]; ti[j-1] = iv;
        }
      }
    }
  }
  float s2 = sum;
#pragma unroll
  for (int o = 32; o; o >>= 1) s2 += __shfl_down(s2, o);
  if ((tid & 63) == 0) red[4 + (tid >> 6)] = s2;

#pragma unroll
  for (int j = 0; j < 8; ++j) { cv[tid * 8 + j] = tv[j]; ci[tid * 8 + j] = ti[j]; }
  __syncthreads();
  const float denom = red[4] + red[5] + red[6] + red[7];

  if (tid < 64) {               // wave 0 merges 2048 candidates, 8 argmax passes
    for (int p = 0; p < 8; ++p) {
      float bv = -INFINITY; int bi = 0x7fffffff;
      for (int q = 0; q < 32; ++q) {
        const int slot = tid + (q << 6);
        const float v = cv[slot]; const int id = ci[slot];
        if (v > bv || (v == bv && id < bi)) { bv = v; bi = id; }
      }
#pragma unroll
      for (int o = 32; o; o >>= 1) {
        const float ov = __shfl_xor(bv, o);
        const int   oi = __shfl_xor(bi, o);
        if (ov > bv || (ov == bv && oi < bi)) { bv = ov; bi = oi; }
      }
      if (tid == 0) { tki[b * 8 + p] = bi; tkw[b * 8 + p] = expf(bv - mx) / denom; }
      for (int q = 0; q < 32; ++q) {
        const int slot = tid + (q << 6);
        if (ci[slot] == bi) cv[slot] = -INFINITY;   // each slot owned by one lane
      }
    }
  }
}

// ---------------------------------------------------------------------------
// xa[b][d] = bf16( x[b][d] + sum_k tkw[b,k] * hout[b*8+k][d] )
// ---------------------------------------------------------------------------
__global__ __launch_bounds__(256)
void k_agg_xa(const float* __restrict__ x, const bf16* __restrict__ hout,
              const float* __restrict__ tkw, bf16* __restrict__ xa)
{
  const long i = (long)blockIdx.x * 256 + threadIdx.x;   // B*D total
  const int b = (int)(i >> 12);                          // D = 4096
  const int d = (int)(i & 4095);
  float a = x[i];
#pragma unroll
  for (int k = 0; k < 8; ++k)
    a += tkw[b * 8 + k] * __bfloat162float(hout[(((long)b * 8 + k) << 12) + d]);
  xa[i] = __float2bfloat16(a);
}

// ---------------------------------------------------------------------------
// conf[b] = sigmoid( final[b,:] . Wc )
// ---------------------------------------------------------------------------
__global__ __launch_bounds__(256)
void k_conf(const float* __restrict__ fin, const float* __restrict__ Wc,
            float* __restrict__ conf)
{
  const int b = blockIdx.x;
  float s = 0.f;
  for (int d = threadIdx.x; d < Dd; d += 256)
    s += fin[(long)b * Dd + d] * Wc[d];
#pragma unroll
  for (int o = 32; o; o >>= 1) s += __shfl_down(s, o);
  __shared__ float r4[4];
  if ((threadIdx.x & 63) == 0) r4[threadIdx.x >> 6] = s;
  __syncthreads();
  if (threadIdx.x == 0) {
    const float t = r4[0] + r4[1] + r4[2] + r4[3];
    conf[b] = 1.f / (1.f + expf(-t));
  }
}

// ---------------------------------------------------------------------------

template<int EPI>
static inline void launch_gemm(const bf16* A, const bf16* Bt, void* C,
                               const bf16* sel, const float* bias, float scale,
                               int M, int N, int K, hipStream_t st)
{
  gemm_nt<EPI><<<dim3(N / 128, M / 128), 256, 0, st>>>(A, Bt, C, sel, bias, scale, M, N, K);
}

extern "C" void kernel_launch(void* const* d_in, const int* in_sizes, int n_in,
                              void* d_out, int out_size, void* d_ws, size_t ws_size,
                              hipStream_t stream)
{
  const float* x   = (const float*)d_in[0];
  const float* ne  = (const float*)d_in[1];
  const float* adj = (const float*)d_in[2];
  const float* Wq  = (const float*)d_in[3];
  const float* Wk  = (const float*)d_in[4];
  const float* W1  = (const float*)d_in[5];
  const float* b1  = (const float*)d_in[6];
  const float* W2  = (const float*)d_in[7];
  const float* b2  = (const float*)d_in[8];
  const float* Wc  = (const float*)d_in[9];
  const float* Wo  = (const float*)d_in[10];
  const float* bo  = (const float*)d_in[11];
  float* out = (float*)d_out;

  // workspace layout (manual lifetime reuse, total 264,273,920 B)
  char* ws = (char*)d_ws;
  bf16*  slot0  = (bf16*)(ws);                 // 64MB: ne_bf16 -> adjG -> hout
  bf16*  slot1  = (bf16*)(ws + 67108864);      // 64MB: keys -> neT -> enh
  bf16*  slotW  = (bf16*)(ws + 134217728);     // 32MB: transposed weight slot
  bf16*  slot3  = (bf16*)(ws + 167772160);     // 32MB: sel -> hmid
  bf16*  slot4  = (bf16*)(ws + 201326592);     // 32MB: msg
  bf16*  xbf    = (bf16*)(ws + 234881024);     // 4MB
  bf16*  qbf    = (bf16*)(ws + 239075328);     // 4MB
  float* scores = (float*)(ws + 243269632);    // 16MB
  int*   tki    = (int*)(ws + 260046848);
  float* tkw    = (float*)(ws + 260063232);
  bf16*  xa     = (bf16*)(ws + 260079616);     // 4MB

  const long neN4 = (long)Nn * Dd / 4;
  const long xN4  = (long)Bsz * Dd / 4;

  // 1. node_emb -> bf16
  k_convert_bf16<<<(int)(neN4 / 256), 256, 0, stream>>>(ne, slot0, neN4);
  // 2. Wk^T
  k_transpose_bf16<<<dim3(64, 64), 256, 0, stream>>>(Wk, slotW, Dd, Dd);
  // 3. keys = ne @ Wk
  launch_gemm<EPI_BF16>(slot0, slotW, slot1, nullptr, nullptr, 1.f, Nn, Dd, Dd, stream);
  // 4. x -> bf16
  k_convert_bf16<<<(int)(xN4 / 256), 256, 0, stream>>>(x, xbf, xN4);
  // 5. Wq^T
  k_transpose_bf16<<<dim3(64, 64), 256, 0, stream>>>(Wq, slotW, Dd, Dd);
  // 6. q = x @ Wq
  launch_gemm<EPI_BF16>(xbf, slotW, qbf, nullptr, nullptr, 1.f, Bsz, Dd, Dd, stream);
  // 7. scores = (q @ keys^T) / 64
  launch_gemm<EPI_SCALE_F32>(qbf, slot1, scores, nullptr, nullptr, 1.f / 64.f,
                             Bsz, Nn, Dd, stream);
  // 8. softmax stats + top-8
  k_softmax_topk<<<Bsz, 256, 0, stream>>>(scores, tki, tkw);
  // 9. sel = node_emb[topk] (bf16)
  k_gather_bf16<<<(int)((long)4096 * Dd / 4 / 256), 256, 0, stream>>>(ne, tki, slot3, Dd);
  // 10. adjG = adj[topk] (bf16)
  k_gather_bf16<<<(int)((long)4096 * Nn / 4 / 256), 256, 0, stream>>>(adj, tki, slot0, Nn);
  // 11. node_emb^T (keys dead)
  k_transpose_bf16<<<dim3(Dd / 64, Nn / 64), 256, 0, stream>>>(ne, slot1, Nn, Dd);
  // 12. msg = adjG @ node_emb
  launch_gemm<EPI_BF16>(slot0, slot1, slot4, nullptr, nullptr, 1.f, 4096, Dd, Nn, stream);
  // 13. enh = sel + 0.1 * (msg @ sel^T)   (neT dead -> enh in slot1)
  launch_gemm<EPI_ENH>(slot4, slot3, slot1, slot3, nullptr, 1.f, 4096, Dd, Dd, stream);
  // 14. W1^T [4096,2048] -> [2048,4096]
  k_transpose_bf16<<<dim3(Hh / 64, Dd / 64), 256, 0, stream>>>(W1, slotW, Dd, Hh);
  // 15. hmid = gelu(enh @ W1 + b1)   (sel dead -> hmid in slot3)
  launch_gemm<EPI_GELU_BIAS>(slot1, slotW, slot3, nullptr, b1, 1.f, 4096, Hh, Dd, stream);
  // 16. W2^T [2048,4096] -> [4096,2048]
  k_transpose_bf16<<<dim3(Dd / 64, Hh / 64), 256, 0, stream>>>(W2, slotW, Hh, Dd);
  // 17. hout = hmid @ W2 + b2   (adjG dead -> hout in slot0)
  launch_gemm<EPI_BIAS_BF16>(slot3, slotW, slot0, nullptr, b2, 1.f, 4096, Dd, Hh, stream);
  // 18. xa = bf16(x + sum_k w*hout)
  k_agg_xa<<<(int)((long)Bsz * Dd / 256), 256, 0, stream>>>(x, slot0, tkw, xa);
  // 19. Wo^T
  k_transpose_bf16<<<dim3(64, 64), 256, 0, stream>>>(Wo, slotW, Dd, Dd);
  // 20. final = xa @ Wo + bo  -> d_out (f32)
  launch_gemm<EPI_BIAS_F32>(xa, slotW, out, nullptr, bo, 1.f, Bsz, Dd, Dd, stream);
  // 21. conf = sigmoid(final @ Wc) -> d_out tail
  k_conf<<<Bsz, 256, 0, stream>>>(out, Wc, out + (long)Bsz * Dd);
}

// Round 2
// 1344.357 us; speedup vs baseline: 1.1398x; 1.1398x over previous
//
#include <hip/hip_runtime.h>
#include <hip/hip_bf16.h>
#include <math.h>

using bf16 = __hip_bfloat16;

typedef __attribute__((ext_vector_type(8))) short short8;   // 8 bf16 (4 VGPR)
typedef __attribute__((ext_vector_type(4))) float f32x4;
typedef __attribute__((ext_vector_type(2))) unsigned int uint2v;

static constexpr int Bsz = 512, Nn = 8192, Dd = 4096, Hh = 2048;

enum { EPI_BF16 = 0, EPI_SCALE_F32, EPI_ENH, EPI_GELU_BIAS, EPI_BIAS_BF16, EPI_BIAS_F32 };

// ---------------------------------------------------------------------------
// async 16B global -> LDS (wave-uniform LDS base + lane*16)
// ---------------------------------------------------------------------------
__device__ __forceinline__ void gload_lds16(const void* g, void* l) {
  __builtin_amdgcn_global_load_lds(
      (const __attribute__((address_space(1))) void*)g,
      (__attribute__((address_space(3))) void*)l, 16, 0, 0);
}

// stage one 128x64 bf16 half-tile (16KB) into LDS region `ldsbase`.
// LDS dest is linear; global source is inverse-swizzled (byte ^= ((row&7)<<4))
// so that a swizzled ds_read sees element (row, kb) at byte row*128 + (kb ^ ((row&7)<<4)).
__device__ __forceinline__ void stage_half(const bf16* __restrict__ g, char* ldsbase,
                                           long grow0, int Kel, long kbyte,
                                           int wave, int lane) {
  const int scb = ((lane & 7) ^ (lane >> 3)) << 4;   // swizzled col-byte
  const long r0 = (wave << 4) + (lane >> 3);         // row of issue 0
  const long pitch = (long)Kel * 2;
  const char* s0 = (const char*)g + (grow0 + r0) * pitch + kbyte + scb;
  const char* s1 = (const char*)g + (grow0 + r0 + 8) * pitch + kbyte + scb;
  gload_lds16(s0, ldsbase + (wave << 11));
  gload_lds16(s1, ldsbase + (wave << 11) + 1024);
}

// ---------------------------------------------------------------------------
// 256x256 8-phase NT GEMM: C[M,N] = A[M,K] @ Bt[N,K]^T  (bf16 in, f32 accum)
// BK=64, 8 waves (2x4), LDS 128KB = 2buf x 2half x (A,B), counted vmcnt(4).
// M,N multiples of 256; K multiple of 64, K >= 128.
// ---------------------------------------------------------------------------
#define READ_A(H)                                                              \
  _Pragma("unroll") for (int mf = 0; mf < 4; ++mf)                             \
  _Pragma("unroll") for (int ks = 0; ks < 2; ++ks)                             \
    aF[mf][ks] = *reinterpret_cast<const short8*>(                             \
        A_c + (H) * 16384 + rowAoff + mf * 2048 + (kA ^ (ks << 6)));

#define READ_B(H)                                                              \
  _Pragma("unroll") for (int nf = 0; nf < 2; ++nf)                             \
  _Pragma("unroll") for (int ks = 0; ks < 2; ++ks)                             \
    bF[nf][ks] = *reinterpret_cast<const short8*>(                             \
        B_c + (H) * 16384 + rowBoff + nf * 2048 + (kA ^ (ks << 6)));

#define PHASE_MFMA(AH, BH)                                                     \
  __builtin_amdgcn_s_barrier();                                                \
  asm volatile("s_waitcnt lgkmcnt(0)" ::: "memory");                           \
  __builtin_amdgcn_sched_barrier(0);                                           \
  __builtin_amdgcn_s_setprio(1);                                               \
  _Pragma("unroll") for (int mf = 0; mf < 4; ++mf)                             \
  _Pragma("unroll") for (int nf = 0; nf < 2; ++nf)                             \
  _Pragma("unroll") for (int ks = 0; ks < 2; ++ks)                             \
    acc[AH][mf][BH][nf] = __builtin_amdgcn_mfma_f32_16x16x32_bf16(             \
        aF[mf][ks], bF[nf][ks], acc[AH][mf][BH][nf], 0, 0, 0);                 \
  __builtin_amdgcn_s_setprio(0);

template<int EPI>
__global__ __launch_bounds__(512, 2)
void gemm_nt_256(const bf16* __restrict__ A, const bf16* __restrict__ Bt,
                 void* __restrict__ Cp, const bf16* __restrict__ sel,
                 const float* __restrict__ bias, float scale,
                 int M, int N, int K)
{
  __shared__ char lds[131072];          // A: [buf][half] 0..65535, B: 65536..
  const int tid  = threadIdx.x;
  const int lane = tid & 63;
  const int wave = tid >> 6;
  const int wm = wave >> 2;             // 0..1
  const int wn = wave & 3;              // 0..3

  // bijective XCD-aware block swizzle (m204)
  const int nblk = (M >> 8) * (N >> 8);
  const int q8 = nblk >> 3, r8 = nblk & 7;
  const int xcd = blockIdx.x & 7, pos = blockIdx.x >> 3;
  const int wg = (xcd < r8 ? xcd * (q8 + 1) : r8 * (q8 + 1) + (xcd - r8) * q8) + pos;
  const int ntx = N >> 8;
  const long bcol = (long)(wg % ntx) << 8;
  const long brow = (long)(wg / ntx) << 8;

  char* const ldsA0 = (char*)lds;
  char* const ldsB0 = (char*)lds + 65536;
  const int rowAoff = (wm * 64 + (lane & 15)) * 128;
  const int rowBoff = (wn * 32 + (lane & 15)) * 128;
  const int kA = (((lane >> 4) ^ (lane & 7)) << 4);

  f32x4 acc[2][4][2][2] = {};           // [ah][mf][bh][nf]
  const int KT = K >> 6;

  // prologue: stage t0{A0,B0,A1,B1}, t1{B0,A1}; wait until t0 landed
  stage_half(A,  ldsA0,          brow,       K, 0,   wave, lane);
  stage_half(Bt, ldsB0,          bcol,       K, 0,   wave, lane);
  stage_half(A,  ldsA0 + 16384,  brow + 128, K, 0,   wave, lane);
  stage_half(Bt, ldsB0 + 16384,  bcol + 128, K, 0,   wave, lane);
  if (KT > 1) {
    stage_half(Bt, ldsB0 + 32768,         bcol,       K, 128, wave, lane);
    stage_half(A,  ldsA0 + 32768 + 16384, brow + 128, K, 128, wave, lane);
  }
  asm volatile("s_waitcnt vmcnt(4)" ::: "memory");
  __builtin_amdgcn_s_barrier();

  for (int t = 0; t < KT; ++t) {
    const int c = t & 1;
    char* const A_c = ldsA0 + c * 32768;
    char* const B_c = ldsB0 + c * 32768;
    const long kb1 = (long)(t + 1) << 7;
    const long kb2 = (long)(t + 2) << 7;
    short8 aF[4][2], bF[2][2];

    // q0: (ah0,bh0); stage A0(t+1) -> buf^1
    READ_A(0); READ_B(0);
    if (t + 1 < KT) stage_half(A, ldsA0 + (c ^ 1) * 32768, brow, K, kb1, wave, lane);
    PHASE_MFMA(0, 0);
    __builtin_amdgcn_s_barrier();

    // q1: (ah1,bh0); stage B1(t+1) -> buf^1
    READ_A(1);
    if (t + 1 < KT) stage_half(Bt, ldsB0 + (c ^ 1) * 32768 + 16384, bcol + 128, K, kb1, wave, lane);
    PHASE_MFMA(1, 0);
    __builtin_amdgcn_s_barrier();

    // q2: (ah1,bh1); stage B0(t+2) -> own buf (freed at q1)
    READ_B(1);
    if (t + 2 < KT) stage_half(Bt, ldsB0 + c * 32768, bcol, K, kb2, wave, lane);
    PHASE_MFMA(1, 1);
    __builtin_amdgcn_s_barrier();

    // q3: (ah0,bh1); stage A1(t+2) -> own buf (freed at q2); counted vmcnt
    READ_A(0);
    if (t + 2 < KT) stage_half(A, ldsA0 + c * 32768 + 16384, brow + 128, K, kb2, wave, lane);
    PHASE_MFMA(0, 1);
    asm volatile("s_waitcnt vmcnt(4)" ::: "memory");
    __builtin_amdgcn_s_barrier();
  }

  // epilogue
#pragma unroll
  for (int ah = 0; ah < 2; ++ah)
#pragma unroll
  for (int mf = 0; mf < 4; ++mf) {
    const long row0 = brow + ah * 128 + wm * 64 + mf * 16 + ((lane >> 4) << 2);
#pragma unroll
    for (int bh = 0; bh < 2; ++bh)
#pragma unroll
    for (int nf = 0; nf < 2; ++nf) {
      const long col = bcol + bh * 128 + wn * 32 + nf * 16 + (lane & 15);
#pragma unroll
      for (int j = 0; j < 4; ++j) {
        const long idx = (row0 + j) * N + col;
        const float v = acc[ah][mf][bh][nf][j];
        if constexpr (EPI == EPI_BF16) {
          reinterpret_cast<bf16*>(Cp)[idx] = __float2bfloat16(v);
        } else if constexpr (EPI == EPI_SCALE_F32) {
          reinterpret_cast<float*>(Cp)[idx] = v * scale;
        } else if constexpr (EPI == EPI_ENH) {
          reinterpret_cast<bf16*>(Cp)[idx] =
              __float2bfloat16(__bfloat162float(sel[idx]) + 0.1f * v);
        } else if constexpr (EPI == EPI_GELU_BIAS) {
          const float tt = v + bias[col];
          reinterpret_cast<bf16*>(Cp)[idx] =
              __float2bfloat16(0.5f * tt * (1.0f + erff(tt * 0.7071067811865475f)));
        } else if constexpr (EPI == EPI_BIAS_BF16) {
          reinterpret_cast<bf16*>(Cp)[idx] = __float2bfloat16(v + bias[col]);
        } else {
          reinterpret_cast<float*>(Cp)[idx] = v + bias[col];
        }
      }
    }
  }
}

// ---------------------------------------------------------------------------
// 128x128 NT GEMM (4 waves) — kept for M=512 GEMMs (q, scores, final)
// ---------------------------------------------------------------------------
template<int EPI>
__global__ __launch_bounds__(256)
void gemm_nt(const bf16* __restrict__ A, const bf16* __restrict__ Bt,
             void* __restrict__ Cp, const bf16* __restrict__ sel,
             const float* __restrict__ bias, float scale,
             int M, int N, int K)
{
  __shared__ bf16 As[128 * 64];
  __shared__ bf16 Bs[128 * 64];
  const int tid  = threadIdx.x;
  const int lane = tid & 63;
  const int wave = tid >> 6;
  const int wm = wave >> 1, wn = wave & 1;
  const long brow = (long)blockIdx.y * 128;
  const long bcol = (long)blockIdx.x * 128;

  f32x4 acc[4][4] = {};

  for (int k0 = 0; k0 < K; k0 += 64) {
    __syncthreads();
#pragma unroll
    for (int i = 0; i < 4; ++i) {
      const int s  = i * 256 + tid;
      const int r  = s >> 3;
      const int cs = s & 7;
      const int col = ((cs ^ (r & 7)) << 3);
      *reinterpret_cast<short8*>(&As[s << 3]) =
          *reinterpret_cast<const short8*>(&A[(brow + r) * K + k0 + col]);
      *reinterpret_cast<short8*>(&Bs[s << 3]) =
          *reinterpret_cast<const short8*>(&Bt[(bcol + r) * K + k0 + col]);
    }
    __syncthreads();
#pragma unroll
    for (int kk = 0; kk < 2; ++kk) {
      short8 af[4], bq[4];
      const int cc = (kk << 2) + (lane >> 4);
#pragma unroll
      for (int m = 0; m < 4; ++m) {
        const int r = wm * 64 + m * 16 + (lane & 15);
        af[m] = *reinterpret_cast<const short8*>(&As[((r << 3) + (cc ^ (r & 7))) << 3]);
      }
#pragma unroll
      for (int n = 0; n < 4; ++n) {
        const int r = wn * 64 + n * 16 + (lane & 15);
        bq[n] = *reinterpret_cast<const short8*>(&Bs[((r << 3) + (cc ^ (r & 7))) << 3]);
      }
#pragma unroll
      for (int m = 0; m < 4; ++m)
#pragma unroll
        for (int n = 0; n < 4; ++n)
          acc[m][n] = __builtin_amdgcn_mfma_f32_16x16x32_bf16(af[m], bq[n], acc[m][n], 0, 0, 0);
    }
  }

#pragma unroll
  for (int m = 0; m < 4; ++m) {
    const long row0 = brow + wm * 64 + m * 16 + ((lane >> 4) << 2);
#pragma unroll
    for (int n = 0; n < 4; ++n) {
      const long col = bcol + wn * 64 + n * 16 + (lane & 15);
#pragma unroll
      for (int j = 0; j < 4; ++j) {
        const long idx = (row0 + j) * N + col;
        const float v = acc[m][n][j];
        if constexpr (EPI == EPI_BF16) {
          reinterpret_cast<bf16*>(Cp)[idx] = __float2bfloat16(v);
        } else if constexpr (EPI == EPI_SCALE_F32) {
          reinterpret_cast<float*>(Cp)[idx] = v * scale;
        } else if constexpr (EPI == EPI_ENH) {
          reinterpret_cast<bf16*>(Cp)[idx] =
              __float2bfloat16(__bfloat162float(sel[idx]) + 0.1f * v);
        } else if constexpr (EPI == EPI_GELU_BIAS) {
          const float t = v + bias[col];
          reinterpret_cast<bf16*>(Cp)[idx] =
              __float2bfloat16(0.5f * t * (1.0f + erff(t * 0.7071067811865475f)));
        } else if constexpr (EPI == EPI_BIAS_BF16) {
          reinterpret_cast<bf16*>(Cp)[idx] = __float2bfloat16(v + bias[col]);
        } else {
          reinterpret_cast<float*>(Cp)[idx] = v + bias[col];
        }
      }
    }
  }
}

// ---------------------------------------------------------------------------
__global__ __launch_bounds__(256)
void k_convert_bf16(const float* __restrict__ in, bf16* __restrict__ out, long n4)
{
  const long i = (long)blockIdx.x * 256 + threadIdx.x;
  if (i >= n4) return;
  const f32x4 v = *reinterpret_cast<const f32x4*>(&in[i * 4]);
  bf16 o[4] __attribute__((aligned(8)));
#pragma unroll
  for (int j = 0; j < 4; ++j) o[j] = __float2bfloat16(v[j]);
  *reinterpret_cast<uint2v*>(&out[i * 4]) = *reinterpret_cast<uint2v*>(o);
}

__global__ __launch_bounds__(256)
void k_transpose_bf16(const float* __restrict__ in, bf16* __restrict__ out, int R, int C)
{
  __shared__ float t[64][65];
  const int bc = blockIdx.x << 6;
  const int br = blockIdx.y << 6;
  for (int i = threadIdx.x; i < 4096; i += 256) {
    const int r = i >> 6, c = i & 63;
    t[r][c] = in[(long)(br + r) * C + (bc + c)];
  }
  __syncthreads();
  for (int i = threadIdx.x; i < 4096; i += 256) {
    const int r = i >> 6, c = i & 63;
    out[(long)(bc + r) * R + (br + c)] = __float2bfloat16(t[c][r]);
  }
}

__global__ __launch_bounds__(256)
void k_gather_bf16(const float* __restrict__ src, const int* __restrict__ map,
                   bf16* __restrict__ dst, int cols)
{
  const long i = (long)blockIdx.x * 256 + threadIdx.x;
  const int cpr = cols >> 2;
  const int row = (int)(i / cpr);
  const int c4  = (int)(i % cpr) << 2;
  const f32x4 v = *reinterpret_cast<const f32x4*>(&src[(long)map[row] * cols + c4]);
  bf16 o[4] __attribute__((aligned(8)));
#pragma unroll
  for (int j = 0; j < 4; ++j) o[j] = __float2bfloat16(v[j]);
  *reinterpret_cast<uint2v*>(&dst[(long)row * cols + c4]) = *reinterpret_cast<uint2v*>(o);
}

__global__ __launch_bounds__(256)
void k_softmax_topk(const float* __restrict__ scores, int* __restrict__ tki,
                    float* __restrict__ tkw)
{
  const int b = blockIdx.x;
  const float* row = scores + (long)b * Nn;
  const int tid = threadIdx.x;
  __shared__ float red[8];
  __shared__ float cv[2048];
  __shared__ int   ci[2048];

  float mx = -INFINITY;
  for (int i = tid; i < Nn; i += 256) mx = fmaxf(mx, row[i]);
#pragma unroll
  for (int o = 32; o; o >>= 1) mx = fmaxf(mx, __shfl_down(mx, o));
  if ((tid & 63) == 0) red[tid >> 6] = mx;
  __syncthreads();
  mx = fmaxf(fmaxf(red[0], red[1]), fmaxf(red[2], red[3]));

  float tv[8]; int ti[8];
#pragma unroll
  for (int j = 0; j < 8; ++j) { tv[j] = -INFINITY; ti[j] = 0x7fffffff; }
  float sum = 0.f;
  for (int i = tid; i < Nn; i += 256) {
    const float v = row[i];
    sum += expf(v - mx);
    if (v > tv[7]) {
      tv[7] = v; ti[7] = i;
#pragma unroll
      for (int j = 7; j > 0; --j) {
        const bool sw = (tv[j] > tv[j-1]) || (tv[j] == tv[j-1] && ti[j] < ti[j-1]);
        if (sw) {
          const float fv = tv[j]; tv[j] = tv[j-1]; tv[j-1] = fv;
          const int   iv = ti[j]; ti[j] = ti[j-1]; ti[j-1] = iv;
        }
      }
    }
  }
  float s2 = sum;
#pragma unroll
  for (int o = 32; o; o >>= 1) s2 += __shfl_down(s2, o);
  if ((tid & 63) == 0) red[4 + (tid >> 6)] = s2;

#pragma unroll
  for (int j = 0; j < 8; ++j) { cv[tid * 8 + j] = tv[j]; ci[tid * 8 + j] = ti[j]; }
  __syncthreads();
  const float denom = red[4] + red[5] + red[6] + red[7];

  if (tid < 64) {
    for (int p = 0; p < 8; ++p) {
      float bv = -INFINITY; int bi = 0x7fffffff;
      for (int q = 0; q < 32; ++q) {
        const int slot = tid + (q << 6);
        const float v = cv[slot]; const int id = ci[slot];
        if (v > bv || (v == bv && id < bi)) { bv = v; bi = id; }
      }
#pragma unroll
      for (int o = 32; o; o >>= 1) {
        const float ov = __shfl_xor(bv, o);
        const int   oi = __shfl_xor(bi, o);
        if (ov > bv || (ov == bv && oi < bi)) { bv = ov; bi = oi; }
      }
      if (tid == 0) { tki[b * 8 + p] = bi; tkw[b * 8 + p] = expf(bv - mx) / denom; }
      for (int q = 0; q < 32; ++q) {
        const int slot = tid + (q << 6);
        if (ci[slot] == bi) cv[slot] = -INFINITY;
      }
    }
  }
}

__global__ __launch_bounds__(256)
void k_agg_xa(const float* __restrict__ x, const bf16* __restrict__ hout,
              const float* __restrict__ tkw, bf16* __restrict__ xa)
{
  const long i = (long)blockIdx.x * 256 + threadIdx.x;
  const int b = (int)(i >> 12);
  const int d = (int)(i & 4095);
  float a = x[i];
#pragma unroll
  for (int k = 0; k < 8; ++k)
    a += tkw[b * 8 + k] * __bfloat162float(hout[(((long)b * 8 + k) << 12) + d]);
  xa[i] = __float2bfloat16(a);
}

__global__ __launch_bounds__(256)
void k_conf(const float* __restrict__ fin, const float* __restrict__ Wc,
            float* __restrict__ conf)
{
  const int b = blockIdx.x;
  float s = 0.f;
  for (int d = threadIdx.x; d < Dd; d += 256)
    s += fin[(long)b * Dd + d] * Wc[d];
#pragma unroll
  for (int o = 32; o; o >>= 1) s += __shfl_down(s, o);
  __shared__ float r4[4];
  if ((threadIdx.x & 63) == 0) r4[threadIdx.x >> 6] = s;
  __syncthreads();
  if (threadIdx.x == 0) {
    const float t = r4[0] + r4[1] + r4[2] + r4[3];
    conf[b] = 1.f / (1.f + expf(-t));
  }
}

// ---------------------------------------------------------------------------
template<int EPI>
static inline void launch_gemm(const bf16* A, const bf16* Bt, void* C,
                               const bf16* sel, const float* bias, float scale,
                               int M, int N, int K, hipStream_t st)
{
  gemm_nt<EPI><<<dim3(N / 128, M / 128), 256, 0, st>>>(A, Bt, C, sel, bias, scale, M, N, K);
}

template<int EPI>
static inline void launch_gemm256(const bf16* A, const bf16* Bt, void* C,
                                  const bf16* sel, const float* bias,
                                  int M, int N, int K, hipStream_t st)
{
  gemm_nt_256<EPI><<<dim3((M >> 8) * (N >> 8)), 512, 0, st>>>(A, Bt, C, sel, bias, 1.f, M, N, K);
}

extern "C" void kernel_launch(void* const* d_in, const int* in_sizes, int n_in,
                              void* d_out, int out_size, void* d_ws, size_t ws_size,
                              hipStream_t stream)
{
  const float* x   = (const float*)d_in[0];
  const float* ne  = (const float*)d_in[1];
  const float* adj = (const float*)d_in[2];
  const float* Wq  = (const float*)d_in[3];
  const float* Wk  = (const float*)d_in[4];
  const float* W1  = (const float*)d_in[5];
  const float* b1  = (const float*)d_in[6];
  const float* W2  = (const float*)d_in[7];
  const float* b2  = (const float*)d_in[8];
  const float* Wc  = (const float*)d_in[9];
  const float* Wo  = (const float*)d_in[10];
  const float* bo  = (const float*)d_in[11];
  float* out = (float*)d_out;

  char* ws = (char*)d_ws;
  bf16*  slot0  = (bf16*)(ws);                 // 64MB: ne_bf16 -> adjG -> hout
  bf16*  slot1  = (bf16*)(ws + 67108864);      // 64MB: keys -> neT -> enh
  bf16*  slotW  = (bf16*)(ws + 134217728);     // 32MB: transposed weight slot
  bf16*  slot3  = (bf16*)(ws + 167772160);     // 32MB: sel -> hmid
  bf16*  slot4  = (bf16*)(ws + 201326592);     // 32MB: msg
  bf16*  xbf    = (bf16*)(ws + 234881024);     // 4MB
  bf16*  qbf    = (bf16*)(ws + 239075328);     // 4MB
  float* scores = (float*)(ws + 243269632);    // 16MB
  int*   tki    = (int*)(ws + 260046848);
  float* tkw    = (float*)(ws + 260063232);
  bf16*  xa     = (bf16*)(ws + 260079616);     // 4MB

  const long neN4 = (long)Nn * Dd / 4;
  const long xN4  = (long)Bsz * Dd / 4;

  // 1. node_emb -> bf16
  k_convert_bf16<<<(int)(neN4 / 256), 256, 0, stream>>>(ne, slot0, neN4);
  // 2. Wk^T
  k_transpose_bf16<<<dim3(64, 64), 256, 0, stream>>>(Wk, slotW, Dd, Dd);
  // 3. keys = ne @ Wk
  launch_gemm256<EPI_BF16>(slot0, slotW, slot1, nullptr, nullptr, Nn, Dd, Dd, stream);
  // 4. x -> bf16
  k_convert_bf16<<<(int)(xN4 / 256), 256, 0, stream>>>(x, xbf, xN4);
  // 5. Wq^T
  k_transpose_bf16<<<dim3(64, 64), 256, 0, stream>>>(Wq, slotW, Dd, Dd);
  // 6. q = x @ Wq  (M=512 -> 128^2 kernel)
  launch_gemm<EPI_BF16>(xbf, slotW, qbf, nullptr, nullptr, 1.f, Bsz, Dd, Dd, stream);
  // 7. scores = (q @ keys^T) / 64
  launch_gemm<EPI_SCALE_F32>(qbf, slot1, scores, nullptr, nullptr, 1.f / 64.f,
                             Bsz, Nn, Dd, stream);
  // 8. softmax stats + top-8
  k_softmax_topk<<<Bsz, 256, 0, stream>>>(scores, tki, tkw);
  // 9. sel = node_emb[topk] (bf16)
  k_gather_bf16<<<(int)((long)4096 * Dd / 4 / 256), 256, 0, stream>>>(ne, tki, slot3, Dd);
  // 10. adjG = adj[topk] (bf16)
  k_gather_bf16<<<(int)((long)4096 * Nn / 4 / 256), 256, 0, stream>>>(adj, tki, slot0, Nn);
  // 11. node_emb^T (keys dead)
  k_transpose_bf16<<<dim3(Dd / 64, Nn / 64), 256, 0, stream>>>(ne, slot1, Nn, Dd);
  // 12. msg = adjG @ node_emb
  launch_gemm256<EPI_BF16>(slot0, slot1, slot4, nullptr, nullptr, 4096, Dd, Nn, stream);
  // 13. enh = sel + 0.1 * (msg @ sel^T)   (neT dead -> enh in slot1)
  launch_gemm256<EPI_ENH>(slot4, slot3, slot1, slot3, nullptr, 4096, Dd, Dd, stream);
  // 14. W1^T
  k_transpose_bf16<<<dim3(Hh / 64, Dd / 64), 256, 0, stream>>>(W1, slotW, Dd, Hh);
  // 15. hmid = gelu(enh @ W1 + b1)   (sel dead -> hmid in slot3)
  launch_gemm256<EPI_GELU_BIAS>(slot1, slotW, slot3, nullptr, b1, 4096, Hh, Dd, stream);
  // 16. W2^T
  k_transpose_bf16<<<dim3(Dd / 64, Hh / 64), 256, 0, stream>>>(W2, slotW, Hh, Dd);
  // 17. hout = hmid @ W2 + b2   (adjG dead -> hout in slot0)
  launch_gemm256<EPI_BIAS_BF16>(slot3, slotW, slot0, nullptr, b2, 4096, Dd, Hh, stream);
  // 18. xa = bf16(x + sum_k w*hout)
  k_agg_xa<<<(int)((long)Bsz * Dd / 256), 256, 0, stream>>>(x, slot0, tkw, xa);
  // 19. Wo^T
  k_transpose_bf16<<<dim3(64, 64), 256, 0, stream>>>(Wo, slotW, Dd, Dd);
  // 20. final = xa @ Wo + bo -> d_out (f32)
  launch_gemm<EPI_BIAS_F32>(xa, slotW, out, nullptr, bo, 1.f, Bsz, Dd, Dd, stream);
  // 21. conf = sigmoid(final @ Wc)
  k_conf<<<Bsz, 256, 0, stream>>>(out, Wc, out + (long)Bsz * Dd);
}

// Round 4
// 1310.831 us; speedup vs baseline: 1.1690x; 1.0256x over previous
//
#include <hip/hip_runtime.h>
#include <hip/hip_bf16.h>
#include <math.h>

using bf16 = __hip_bfloat16;

typedef __attribute__((ext_vector_type(8))) short short8;   // 8 bf16 (4 VGPR)
typedef __attribute__((ext_vector_type(4))) float f32x4;
typedef __attribute__((ext_vector_type(2))) unsigned int uint2v;

static constexpr int Bsz = 512, Nn = 8192, Dd = 4096, Hh = 2048;

enum { EPI_BF16 = 0, EPI_SCALE_F32, EPI_ENH, EPI_GELU_BIAS, EPI_BIAS_BF16, EPI_BIAS_F32 };

// ---------------------------------------------------------------------------
// async 16B global -> LDS (wave-uniform LDS base + lane*16)
// ---------------------------------------------------------------------------
__device__ __forceinline__ void gload_lds16(const void* g, void* l) {
  __builtin_amdgcn_global_load_lds(
      (const __attribute__((address_space(1))) void*)g,
      (__attribute__((address_space(3))) void*)l, 16, 0, 0);
}

// stage one 128x64 bf16 half-tile (16KB) into LDS region `ldsbase`.
// LDS dest is linear; global source is inverse-swizzled (byte ^= ((row&7)<<4))
// so a swizzled ds_read sees element (row,kb) at byte row*128 + (kb ^ ((row&7)<<4)).
__device__ __forceinline__ void stage_half(const bf16* __restrict__ g, char* ldsbase,
                                           long grow0, int Kel, long kbyte,
                                           int wave, int lane) {
  const int scb = ((lane & 7) ^ (lane >> 3)) << 4;   // swizzled col-byte
  const long r0 = (wave << 4) + (lane >> 3);         // row of issue 0
  const long pitch = (long)Kel * 2;
  const char* s0 = (const char*)g + (grow0 + r0) * pitch + kbyte + scb;
  const char* s1 = (const char*)g + (grow0 + r0 + 8) * pitch + kbyte + scb;
  gload_lds16(s0, ldsbase + (wave << 11));
  gload_lds16(s1, ldsbase + (wave << 11) + 1024);
}

// ---------------------------------------------------------------------------
// 256x256 NT GEMM: C[M,N] = A[M,K] @ Bt[N,K]^T  (bf16 in, f32 accum)
// BK=64, 8 waves (2x4), LDS 128KB = 2buf x 2half x (A,B).
// TWO barriers per K-tile (prologue-pattern: own-vmcnt -> barrier -> read);
// stage FIFO order B0,A0,A1,B1; counted vmcnt (never 0) keeps 2-8 loads in
// flight across barriers. ds_read prefetch one phase ahead; compiler's
// counted lgkmcnt lets MFMA overlap in-flight reads.
// Cross-wave safety ledger:
//   tile-entry barrier guarantees B0,A0,A1 of tile t landed (vmcnt(2):
//     outstanding {B0,A0,A1,B1}(t) -> drains first 3).
//   mid-tile barrier guarantees B1(t) landed (vmcnt(4): outstanding
//     {B1(t),B0(t+1),A0(t+1)} -> drains B1(t)).
// M,N multiples of 256; K multiple of 64, K >= 128.
// ---------------------------------------------------------------------------
#define READ_AF(DST, H)                                                        \
  _Pragma("unroll") for (int mf = 0; mf < 4; ++mf)                             \
  _Pragma("unroll") for (int ks = 0; ks < 2; ++ks)                             \
    DST[mf][ks] = *reinterpret_cast<const short8*>(                            \
        A_c + (H) * 16384 + rowAoff + mf * 2048 + (kA ^ (ks << 6)));

#define READ_BF(DST, H)                                                        \
  _Pragma("unroll") for (int nf = 0; nf < 2; ++nf)                             \
  _Pragma("unroll") for (int ks = 0; ks < 2; ++ks)                             \
    DST[nf][ks] = *reinterpret_cast<const short8*>(                            \
        B_c + (H) * 16384 + rowBoff + nf * 2048 + (kA ^ (ks << 6)));

// ks outermost: consecutive MFMAs hit different acc regs (no dep stalls)
#define MFMA_Q(AH, AV, BH, BV)                                                 \
  __builtin_amdgcn_s_setprio(1);                                               \
  _Pragma("unroll") for (int ks = 0; ks < 2; ++ks)                             \
  _Pragma("unroll") for (int mf = 0; mf < 4; ++mf)                             \
  _Pragma("unroll") for (int nf = 0; nf < 2; ++nf)                             \
    acc[AH][mf][BH][nf] = __builtin_amdgcn_mfma_f32_16x16x32_bf16(             \
        AV[mf][ks], BV[nf][ks], acc[AH][mf][BH][nf], 0, 0, 0);                 \
  __builtin_amdgcn_s_setprio(0);

#define VMCNT2 asm volatile("s_waitcnt vmcnt(2)" ::: "memory")
#define VMCNT4 asm volatile("s_waitcnt vmcnt(4)" ::: "memory")

template<int EPI>
__global__ __launch_bounds__(512, 1)
void gemm_nt_256(const bf16* __restrict__ A, const bf16* __restrict__ Bt,
                 void* __restrict__ Cp, const bf16* __restrict__ sel,
                 const float* __restrict__ bias, float scale,
                 int M, int N, int K)
{
  __shared__ char lds[131072];          // A: [buf][half] 0..65535, B: 65536..
  const int tid  = threadIdx.x;
  const int lane = tid & 63;
  const int wave = tid >> 6;
  const int wm = wave >> 2;             // 0..1
  const int wn = wave & 3;              // 0..3

  // bijective XCD-aware block swizzle (m204)
  const int nblk = (M >> 8) * (N >> 8);
  const int q8 = nblk >> 3, r8 = nblk & 7;
  const int xcd = blockIdx.x & 7, pos = blockIdx.x >> 3;
  const int wg = (xcd < r8 ? xcd * (q8 + 1) : r8 * (q8 + 1) + (xcd - r8) * q8) + pos;
  const int ntx = N >> 8;
  const long bcol = (long)(wg % ntx) << 8;
  const long brow = (long)(wg / ntx) << 8;

  char* const ldsA0 = (char*)lds;
  char* const ldsB0 = (char*)lds + 65536;
  const int rowAoff = (wm * 64 + (lane & 15)) * 128;
  const int rowBoff = (wn * 32 + (lane & 15)) * 128;
  const int kA = (((lane >> 4) ^ (lane & 7)) << 4);

  f32x4 acc[2][4][2][2] = {};           // [ah][mf][bh][nf]
  const int KT = K >> 6;

  // prologue: stage tile 0 in FIFO order B0,A0,A1,B1 -> buf0
  stage_half(Bt, ldsB0,          bcol,       K, 0, wave, lane);
  stage_half(A,  ldsA0,          brow,       K, 0, wave, lane);
  stage_half(A,  ldsA0 + 16384,  brow + 128, K, 0, wave, lane);
  stage_half(Bt, ldsB0 + 16384,  bcol + 128, K, 0, wave, lane);
  VMCNT2;                               // B0,A0,A1 landed; B1 may be in flight
  __builtin_amdgcn_s_barrier();

  for (int t = 0; t < KT; ++t) {
    const int c = t & 1;
    char* const A_c = ldsA0 + c * 32768;
    char* const B_c = ldsB0 + c * 32768;
    char* const A_n = ldsA0 + (c ^ 1) * 32768;
    char* const B_n = ldsB0 + (c ^ 1) * 32768;
    const int tn = (t + 1 < KT) ? (t + 1) : t;      // clamp keeps FIFO uniform
    const long kbn = (long)tn << 7;
    short8 aF[4][2], aG[4][2], bF[2][2], bG[2][2];

    // p0: MFMA (0,0); prefetch A1; stage B0(t+1)
    stage_half(Bt, B_n, bcol, K, kbn, wave, lane);
    READ_AF(aF, 0); READ_BF(bF, 0);
    READ_AF(aG, 1);                     // prefetch for p1 (counted lgkm overlap)
    MFMA_Q(0, aF, 0, bF);

    // p1: MFMA (1,0) [aG, bF kept]; stage A0(t+1); fence B1(t)
    stage_half(A, A_n, brow, K, kbn, wave, lane);
    MFMA_Q(1, aG, 0, bF);
    VMCNT4;                             // own B1(t) landed
    __builtin_amdgcn_s_barrier();       // ALL waves' B1(t) landed

    // p2: MFMA (1,1) [aG kept]; read B1; prefetch A0 re-read; stage A1(t+1)
    stage_half(A, A_n + 16384, brow + 128, K, kbn, wave, lane);
    READ_BF(bG, 1);
    READ_AF(aF, 0);                     // prefetch for p3
    MFMA_Q(1, aG, 1, bG);

    // p3: MFMA (0,1) [aF, bG kept]; stage B1(t+1); tile fence
    stage_half(Bt, B_n + 16384, bcol + 128, K, kbn, wave, lane);
    MFMA_Q(0, aF, 1, bG);
    VMCNT2;                             // own B0,A0,A1 (t+1) landed
    __builtin_amdgcn_s_barrier();       // ALL waves' B0,A0,A1 (t+1) landed
  }

  // epilogue
#pragma unroll
  for (int ah = 0; ah < 2; ++ah)
#pragma unroll
  for (int mf = 0; mf < 4; ++mf) {
    const long row0 = brow + ah * 128 + wm * 64 + mf * 16 + ((lane >> 4) << 2);
#pragma unroll
    for (int bh = 0; bh < 2; ++bh)
#pragma unroll
    for (int nf = 0; nf < 2; ++nf) {
      const long col = bcol + bh * 128 + wn * 32 + nf * 16 + (lane & 15);
#pragma unroll
      for (int j = 0; j < 4; ++j) {
        const long idx = (row0 + j) * N + col;
        const float v = acc[ah][mf][bh][nf][j];
        if constexpr (EPI == EPI_BF16) {
          reinterpret_cast<bf16*>(Cp)[idx] = __float2bfloat16(v);
        } else if constexpr (EPI == EPI_SCALE_F32) {
          reinterpret_cast<float*>(Cp)[idx] = v * scale;
        } else if constexpr (EPI == EPI_ENH) {
          reinterpret_cast<bf16*>(Cp)[idx] =
              __float2bfloat16(__bfloat162float(sel[idx]) + 0.1f * v);
        } else if constexpr (EPI == EPI_GELU_BIAS) {
          const float tt = v + bias[col];
          reinterpret_cast<bf16*>(Cp)[idx] =
              __float2bfloat16(0.5f * tt * (1.0f + erff(tt * 0.7071067811865475f)));
        } else if constexpr (EPI == EPI_BIAS_BF16) {
          reinterpret_cast<bf16*>(Cp)[idx] = __float2bfloat16(v + bias[col]);
        } else {
          reinterpret_cast<float*>(Cp)[idx] = v + bias[col];
        }
      }
    }
  }
}

// ---------------------------------------------------------------------------
// 128x128 NT GEMM (4 waves) — kept for M=512 GEMMs (q, scores, final)
// ---------------------------------------------------------------------------
template<int EPI>
__global__ __launch_bounds__(256)
void gemm_nt(const bf16* __restrict__ A, const bf16* __restrict__ Bt,
             void* __restrict__ Cp, const bf16* __restrict__ sel,
             const float* __restrict__ bias, float scale,
             int M, int N, int K)
{
  __shared__ bf16 As[128 * 64];
  __shared__ bf16 Bs[128 * 64];
  const int tid  = threadIdx.x;
  const int lane = tid & 63;
  const int wave = tid >> 6;
  const int wm = wave >> 1, wn = wave & 1;
  const long brow = (long)blockIdx.y * 128;
  const long bcol = (long)blockIdx.x * 128;

  f32x4 acc[4][4] = {};

  for (int k0 = 0; k0 < K; k0 += 64) {
    __syncthreads();
#pragma unroll
    for (int i = 0; i < 4; ++i) {
      const int s  = i * 256 + tid;
      const int r  = s >> 3;
      const int cs = s & 7;
      const int col = ((cs ^ (r & 7)) << 3);
      *reinterpret_cast<short8*>(&As[s << 3]) =
          *reinterpret_cast<const short8*>(&A[(brow + r) * K + k0 + col]);
      *reinterpret_cast<short8*>(&Bs[s << 3]) =
          *reinterpret_cast<const short8*>(&Bt[(bcol + r) * K + k0 + col]);
    }
    __syncthreads();
#pragma unroll
    for (int kk = 0; kk < 2; ++kk) {
      short8 af[4], bq[4];
      const int cc = (kk << 2) + (lane >> 4);
#pragma unroll
      for (int m = 0; m < 4; ++m) {
        const int r = wm * 64 + m * 16 + (lane & 15);
        af[m] = *reinterpret_cast<const short8*>(&As[((r << 3) + (cc ^ (r & 7))) << 3]);
      }
#pragma unroll
      for (int n = 0; n < 4; ++n) {
        const int r = wn * 64 + n * 16 + (lane & 15);
        bq[n] = *reinterpret_cast<const short8*>(&Bs[((r << 3) + (cc ^ (r & 7))) << 3]);
      }
#pragma unroll
      for (int m = 0; m < 4; ++m)
#pragma unroll
        for (int n = 0; n < 4; ++n)
          acc[m][n] = __builtin_amdgcn_mfma_f32_16x16x32_bf16(af[m], bq[n], acc[m][n], 0, 0, 0);
    }
  }

#pragma unroll
  for (int m = 0; m < 4; ++m) {
    const long row0 = brow + wm * 64 + m * 16 + ((lane >> 4) << 2);
#pragma unroll
    for (int n = 0; n < 4; ++n) {
      const long col = bcol + wn * 64 + n * 16 + (lane & 15);
#pragma unroll
      for (int j = 0; j < 4; ++j) {
        const long idx = (row0 + j) * N + col;
        const float v = acc[m][n][j];
        if constexpr (EPI == EPI_BF16) {
          reinterpret_cast<bf16*>(Cp)[idx] = __float2bfloat16(v);
        } else if constexpr (EPI == EPI_SCALE_F32) {
          reinterpret_cast<float*>(Cp)[idx] = v * scale;
        } else if constexpr (EPI == EPI_ENH) {
          reinterpret_cast<bf16*>(Cp)[idx] =
              __float2bfloat16(__bfloat162float(sel[idx]) + 0.1f * v);
        } else if constexpr (EPI == EPI_GELU_BIAS) {
          const float t = v + bias[col];
          reinterpret_cast<bf16*>(Cp)[idx] =
              __float2bfloat16(0.5f * t * (1.0f + erff(t * 0.7071067811865475f)));
        } else if constexpr (EPI == EPI_BIAS_BF16) {
          reinterpret_cast<bf16*>(Cp)[idx] = __float2bfloat16(v + bias[col]);
        } else {
          reinterpret_cast<float*>(Cp)[idx] = v + bias[col];
        }
      }
    }
  }
}

// ---------------------------------------------------------------------------
__global__ __launch_bounds__(256)
void k_convert_bf16(const float* __restrict__ in, bf16* __restrict__ out, long n4)
{
  const long i = (long)blockIdx.x * 256 + threadIdx.x;
  if (i >= n4) return;
  const f32x4 v = *reinterpret_cast<const f32x4*>(&in[i * 4]);
  bf16 o[4] __attribute__((aligned(8)));
#pragma unroll
  for (int j = 0; j < 4; ++j) o[j] = __float2bfloat16(v[j]);
  *reinterpret_cast<uint2v*>(&out[i * 4]) = *reinterpret_cast<uint2v*>(o);
}

__global__ __launch_bounds__(256)
void k_transpose_bf16(const float* __restrict__ in, bf16* __restrict__ out, int R, int C)
{
  __shared__ float t[64][65];
  const int bc = blockIdx.x << 6;
  const int br = blockIdx.y << 6;
  for (int i = threadIdx.x; i < 4096; i += 256) {
    const int r = i >> 6, c = i & 63;
    t[r][c] = in[(long)(br + r) * C + (bc + c)];
  }
  __syncthreads();
  for (int i = threadIdx.x; i < 4096; i += 256) {
    const int r = i >> 6, c = i & 63;
    out[(long)(bc + r) * R + (br + c)] = __float2bfloat16(t[c][r]);
  }
}

__global__ __launch_bounds__(256)
void k_gather_bf16(const float* __restrict__ src, const int* __restrict__ map,
                   bf16* __restrict__ dst, int cols)
{
  const long i = (long)blockIdx.x * 256 + threadIdx.x;
  const int cpr = cols >> 2;
  const int row = (int)(i / cpr);
  const int c4  = (int)(i % cpr) << 2;
  const f32x4 v = *reinterpret_cast<const f32x4*>(&src[(long)map[row] * cols + c4]);
  bf16 o[4] __attribute__((aligned(8)));
#pragma unroll
  for (int j = 0; j < 4; ++j) o[j] = __float2bfloat16(v[j]);
  *reinterpret_cast<uint2v*>(&dst[(long)row * cols + c4]) = *reinterpret_cast<uint2v*>(o);
}

__global__ __launch_bounds__(256)
void k_softmax_topk(const float* __restrict__ scores, int* __restrict__ tki,
                    float* __restrict__ tkw)
{
  const int b = blockIdx.x;
  const float* row = scores + (long)b * Nn;
  const int tid = threadIdx.x;
  __shared__ float red[8];
  __shared__ float cv[2048];
  __shared__ int   ci[2048];

  float mx = -INFINITY;
  for (int i = tid; i < Nn; i += 256) mx = fmaxf(mx, row[i]);
#pragma unroll
  for (int o = 32; o; o >>= 1) mx = fmaxf(mx, __shfl_down(mx, o));
  if ((tid & 63) == 0) red[tid >> 6] = mx;
  __syncthreads();
  mx = fmaxf(fmaxf(red[0], red[1]), fmaxf(red[2], red[3]));

  float tv[8]; int ti[8];
#pragma unroll
  for (int j = 0; j < 8; ++j) { tv[j] = -INFINITY; ti[j] = 0x7fffffff; }
  float sum = 0.f;
  for (int i = tid; i < Nn; i += 256) {
    const float v = row[i];
    sum += expf(v - mx);
    if (v > tv[7]) {
      tv[7] = v; ti[7] = i;
#pragma unroll
      for (int j = 7; j > 0; --j) {
        const bool sw = (tv[j] > tv[j-1]) || (tv[j] == tv[j-1] && ti[j] < ti[j-1]);
        if (sw) {
          const float fv = tv[j]; tv[j] = tv[j-1]; tv[j-1] = fv;
          const int   iv = ti[j]; ti[j] = ti[j-1]; ti[j-1] = iv;
        }
      }
    }
  }
  float s2 = sum;
#pragma unroll
  for (int o = 32; o; o >>= 1) s2 += __shfl_down(s2, o);
  if ((tid & 63) == 0) red[4 + (tid >> 6)] = s2;

#pragma unroll
  for (int j = 0; j < 8; ++j) { cv[tid * 8 + j] = tv[j]; ci[tid * 8 + j] = ti[j]; }
  __syncthreads();
  const float denom = red[4] + red[5] + red[6] + red[7];

  if (tid < 64) {
    for (int p = 0; p < 8; ++p) {
      float bv = -INFINITY; int bi = 0x7fffffff;
      for (int q = 0; q < 32; ++q) {
        const int slot = tid + (q << 6);
        const float v = cv[slot]; const int id = ci[slot];
        if (v > bv || (v == bv && id < bi)) { bv = v; bi = id; }
      }
#pragma unroll
      for (int o = 32; o; o >>= 1) {
        const float ov = __shfl_xor(bv, o);
        const int   oi = __shfl_xor(bi, o);
        if (ov > bv || (ov == bv && oi < bi)) { bv = ov; bi = oi; }
      }
      if (tid == 0) { tki[b * 8 + p] = bi; tkw[b * 8 + p] = expf(bv - mx) / denom; }
      for (int q = 0; q < 32; ++q) {
        const int slot = tid + (q << 6);
        if (ci[slot] == bi) cv[slot] = -INFINITY;
      }
    }
  }
}

__global__ __launch_bounds__(256)
void k_agg_xa(const float* __restrict__ x, const bf16* __restrict__ hout,
              const float* __restrict__ tkw, bf16* __restrict__ xa)
{
  const long i = (long)blockIdx.x * 256 + threadIdx.x;
  const int b = (int)(i >> 12);
  const int d = (int)(i & 4095);
  float a = x[i];
#pragma unroll
  for (int k = 0; k < 8; ++k)
    a += tkw[b * 8 + k] * __bfloat162float(hout[(((long)b * 8 + k) << 12) + d]);
  xa[i] = __float2bfloat16(a);
}

__global__ __launch_bounds__(256)
void k_conf(const float* __restrict__ fin, const float* __restrict__ Wc,
            float* __restrict__ conf)
{
  const int b = blockIdx.x;
  float s = 0.f;
  for (int d = threadIdx.x; d < Dd; d += 256)
    s += fin[(long)b * Dd + d] * Wc[d];
#pragma unroll
  for (int o = 32; o; o >>= 1) s += __shfl_down(s, o);
  __shared__ float r4[4];
  if ((threadIdx.x & 63) == 0) r4[threadIdx.x >> 6] = s;
  __syncthreads();
  if (threadIdx.x == 0) {
    const float t = r4[0] + r4[1] + r4[2] + r4[3];
    conf[b] = 1.f / (1.f + expf(-t));
  }
}

// ---------------------------------------------------------------------------
template<int EPI>
static inline void launch_gemm(const bf16* A, const bf16* Bt, void* C,
                               const bf16* sel, const float* bias, float scale,
                               int M, int N, int K, hipStream_t st)
{
  gemm_nt<EPI><<<dim3(N / 128, M / 128), 256, 0, st>>>(A, Bt, C, sel, bias, scale, M, N, K);
}

template<int EPI>
static inline void launch_gemm256(const bf16* A, const bf16* Bt, void* C,
                                  const bf16* sel, const float* bias,
                                  int M, int N, int K, hipStream_t st)
{
  gemm_nt_256<EPI><<<dim3((M >> 8) * (N >> 8)), 512, 0, st>>>(A, Bt, C, sel, bias, 1.f, M, N, K);
}

extern "C" void kernel_launch(void* const* d_in, const int* in_sizes, int n_in,
                              void* d_out, int out_size, void* d_ws, size_t ws_size,
                              hipStream_t stream)
{
  const float* x   = (const float*)d_in[0];
  const float* ne  = (const float*)d_in[1];
  const float* adj = (const float*)d_in[2];
  const float* Wq  = (const float*)d_in[3];
  const float* Wk  = (const float*)d_in[4];
  const float* W1  = (const float*)d_in[5];
  const float* b1  = (const float*)d_in[6];
  const float* W2  = (const float*)d_in[7];
  const float* b2  = (const float*)d_in[8];
  const float* Wc  = (const float*)d_in[9];
  const float* Wo  = (const float*)d_in[10];
  const float* bo  = (const float*)d_in[11];
  float* out = (float*)d_out;

  char* ws = (char*)d_ws;
  bf16*  slot0  = (bf16*)(ws);                 // 64MB: ne_bf16 -> adjG -> hout
  bf16*  slot1  = (bf16*)(ws + 67108864);      // 64MB: keys -> neT -> enh
  bf16*  slotW  = (bf16*)(ws + 134217728);     // 32MB: transposed weight slot
  bf16*  slot3  = (bf16*)(ws + 167772160);     // 32MB: sel -> hmid
  bf16*  slot4  = (bf16*)(ws + 201326592);     // 32MB: msg
  bf16*  xbf    = (bf16*)(ws + 234881024);     // 4MB
  bf16*  qbf    = (bf16*)(ws + 239075328);     // 4MB
  float* scores = (float*)(ws + 243269632);    // 16MB
  int*   tki    = (int*)(ws + 260046848);
  float* tkw    = (float*)(ws + 260063232);
  bf16*  xa     = (bf16*)(ws + 260079616);     // 4MB

  const long neN4 = (long)Nn * Dd / 4;
  const long xN4  = (long)Bsz * Dd / 4;

  // 1. node_emb -> bf16
  k_convert_bf16<<<(int)(neN4 / 256), 256, 0, stream>>>(ne, slot0, neN4);
  // 2. Wk^T
  k_transpose_bf16<<<dim3(64, 64), 256, 0, stream>>>(Wk, slotW, Dd, Dd);
  // 3. keys = ne @ Wk
  launch_gemm256<EPI_BF16>(slot0, slotW, slot1, nullptr, nullptr, Nn, Dd, Dd, stream);
  // 4. x -> bf16
  k_convert_bf16<<<(int)(xN4 / 256), 256, 0, stream>>>(x, xbf, xN4);
  // 5. Wq^T
  k_transpose_bf16<<<dim3(64, 64), 256, 0, stream>>>(Wq, slotW, Dd, Dd);
  // 6. q = x @ Wq  (M=512 -> 128^2 kernel)
  launch_gemm<EPI_BF16>(xbf, slotW, qbf, nullptr, nullptr, 1.f, Bsz, Dd, Dd, stream);
  // 7. scores = (q @ keys^T) / 64
  launch_gemm<EPI_SCALE_F32>(qbf, slot1, scores, nullptr, nullptr, 1.f / 64.f,
                             Bsz, Nn, Dd, stream);
  // 8. softmax stats + top-8
  k_softmax_topk<<<Bsz, 256, 0, stream>>>(scores, tki, tkw);
  // 9. sel = node_emb[topk] (bf16)
  k_gather_bf16<<<(int)((long)4096 * Dd / 4 / 256), 256, 0, stream>>>(ne, tki, slot3, Dd);
  // 10. adjG = adj[topk] (bf16)
  k_gather_bf16<<<(int)((long)4096 * Nn / 4 / 256), 256, 0, stream>>>(adj, tki, slot0, Nn);
  // 11. node_emb^T (keys dead)
  k_transpose_bf16<<<dim3(Dd / 64, Nn / 64), 256, 0, stream>>>(ne, slot1, Nn, Dd);
  // 12. msg = adjG @ node_emb
  launch_gemm256<EPI_BF16>(slot0, slot1, slot4, nullptr, nullptr, 4096, Dd, Nn, stream);
  // 13. enh = sel + 0.1 * (msg @ sel^T)   (neT dead -> enh in slot1)
  launch_gemm256<EPI_ENH>(slot4, slot3, slot1, slot3, nullptr, 4096, Dd, Dd, stream);
  // 14. W1^T
  k_transpose_bf16<<<dim3(Hh / 64, Dd / 64), 256, 0, stream>>>(W1, slotW, Dd, Hh);
  // 15. hmid = gelu(enh @ W1 + b1)   (sel dead -> hmid in slot3)
  launch_gemm256<EPI_GELU_BIAS>(slot1, slotW, slot3, nullptr, b1, 4096, Hh, Dd, stream);
  // 16. W2^T
  k_transpose_bf16<<<dim3(Dd / 64, Hh / 64), 256, 0, stream>>>(W2, slotW, Hh, Dd);
  // 17. hout = hmid @ W2 + b2   (adjG dead -> hout in slot0)
  launch_gemm256<EPI_BIAS_BF16>(slot3, slotW, slot0, nullptr, b2, 4096, Dd, Hh, stream);
  // 18. xa = bf16(x + sum_k w*hout)
  k_agg_xa<<<(int)((long)Bsz * Dd / 256), 256, 0, stream>>>(x, slot0, tkw, xa);
  // 19. Wo^T
  k_transpose_bf16<<<dim3(64, 64), 256, 0, stream>>>(Wo, slotW, Dd, Dd);
  // 20. final = xa @ Wo + bo -> d_out (f32)
  launch_gemm<EPI_BIAS_F32>(xa, slotW, out, nullptr, bo, 1.f, Bsz, Dd, Dd, stream);
  // 21. conf = sigmoid(final @ Wc)
  k_conf<<<Bsz, 256, 0, stream>>>(out, Wc, out + (long)Bsz * Dd);
}

// Round 5
// 1281.822 us; speedup vs baseline: 1.1954x; 1.0226x over previous
//
#include <hip/hip_runtime.h>
#include <hip/hip_bf16.h>
#include <math.h>

using bf16 = __hip_bfloat16;

typedef __attribute__((ext_vector_type(8))) short short8;   // 8 bf16 (4 VGPR)
typedef __attribute__((ext_vector_type(4))) float f32x4;
typedef __attribute__((ext_vector_type(2))) unsigned int uint2v;

static constexpr int Bsz = 512, Nn = 8192, Dd = 4096, Hh = 2048;

enum { EPI_BF16 = 0, EPI_SCALE_F32, EPI_ENH, EPI_GELU_BIAS, EPI_BIAS_BF16, EPI_BIAS_F32 };

// ---------------------------------------------------------------------------
// async 16B global -> LDS (wave-uniform LDS base + lane*16)
// ---------------------------------------------------------------------------
__device__ __forceinline__ void gload_lds16(const void* g, void* l) {
  __builtin_amdgcn_global_load_lds(
      (const __attribute__((address_space(1))) void*)g,
      (__attribute__((address_space(3))) void*)l, 16, 0, 0);
}

// stage one 128x64 bf16 half-tile (16KB) into LDS region `ldsbase`.
// LDS dest is linear; global source is inverse-swizzled (byte ^= ((row&7)<<4))
// so a swizzled ds_read sees element (row,kb) at byte row*128 + (kb ^ ((row&7)<<4)).
__device__ __forceinline__ void stage_half(const bf16* __restrict__ g, char* ldsbase,
                                           long grow0, int Kel, long kbyte,
                                           int wave, int lane) {
  const int scb = ((lane & 7) ^ (lane >> 3)) << 4;   // swizzled col-byte
  const long r0 = (wave << 4) + (lane >> 3);         // row of issue 0
  const long pitch = (long)Kel * 2;
  const char* s0 = (const char*)g + (grow0 + r0) * pitch + kbyte + scb;
  const char* s1 = (const char*)g + (grow0 + r0 + 8) * pitch + kbyte + scb;
  gload_lds16(s0, ldsbase + (wave << 11));
  gload_lds16(s1, ldsbase + (wave << 11) + 1024);
}

// ---------------------------------------------------------------------------
// 256x256 NT GEMM: C[M,N] = A[M,K] @ Bt[N,K]^T  (bf16 in, f32 accum)
// BK=64, 8 waves (2x4), LDS 128KB = 2buf x 2half x (A,B).
// Stage FIFO order B0,B1,A0,A1 so the ENTRY fence covers {B0,B1,A0}: all of
// aF,bF,bG read up-front in p0 (full fragment reuse, 24 ds_read_b128/tile),
// mid-tile fence only covers A1 (aG). Two barriers/tile, counted vmcnt only.
// Ledger (2 loads/half, steady state, per wave):
//   entry: outstanding = {A1(t)}          (end-of-prev vmcnt(2))
//   mid  : outstanding = {A1(t),B0',B1'}  -> vmcnt(4) drains A1(t), barrier
//   end  : outstanding = {B0',B1',A0',A1'} -> vmcnt(2) drains B0',B1',A0'
// M,N multiples of 256; K multiple of 64, K >= 128.
// ---------------------------------------------------------------------------
#define READ_AF(DST, H)                                                        \
  _Pragma("unroll") for (int mf = 0; mf < 4; ++mf)                             \
  _Pragma("unroll") for (int ks = 0; ks < 2; ++ks)                             \
    DST[mf][ks] = *reinterpret_cast<const short8*>(                            \
        A_c + (H) * 16384 + rowAoff + mf * 2048 + (kA ^ (ks << 6)));

#define READ_BF(DST, H)                                                        \
  _Pragma("unroll") for (int nf = 0; nf < 2; ++nf)                             \
  _Pragma("unroll") for (int ks = 0; ks < 2; ++ks)                             \
    DST[nf][ks] = *reinterpret_cast<const short8*>(                            \
        B_c + (H) * 16384 + rowBoff + nf * 2048 + (kA ^ (ks << 6)));

// ks outermost: consecutive MFMAs hit different acc regs (no dep stalls)
#define MFMA_Q(AH, AV, BH, BV)                                                 \
  __builtin_amdgcn_s_setprio(1);                                               \
  _Pragma("unroll") for (int ks = 0; ks < 2; ++ks)                             \
  _Pragma("unroll") for (int mf = 0; mf < 4; ++mf)                             \
  _Pragma("unroll") for (int nf = 0; nf < 2; ++nf)                             \
    acc[AH][mf][BH][nf] = __builtin_amdgcn_mfma_f32_16x16x32_bf16(             \
        AV[mf][ks], BV[nf][ks], acc[AH][mf][BH][nf], 0, 0, 0);                 \
  __builtin_amdgcn_s_setprio(0);

#define VMCNT2 asm volatile("s_waitcnt vmcnt(2)" ::: "memory")
#define VMCNT4 asm volatile("s_waitcnt vmcnt(4)" ::: "memory")

template<int EPI>
__global__ __launch_bounds__(512, 1)
void gemm_nt_256(const bf16* __restrict__ A, const bf16* __restrict__ Bt,
                 void* __restrict__ Cp, const bf16* __restrict__ sel,
                 const float* __restrict__ bias, float scale,
                 int M, int N, int K)
{
  __shared__ char lds[131072];          // A: [buf][half] 0..65535, B: 65536..
  const int tid  = threadIdx.x;
  const int lane = tid & 63;
  const int wave = tid >> 6;
  const int wm = wave >> 2;             // 0..1
  const int wn = wave & 3;              // 0..3

  // bijective XCD-aware block swizzle (m204)
  const int nblk = (M >> 8) * (N >> 8);
  const int q8 = nblk >> 3, r8 = nblk & 7;
  const int xcd = blockIdx.x & 7, pos = blockIdx.x >> 3;
  const int wg = (xcd < r8 ? xcd * (q8 + 1) : r8 * (q8 + 1) + (xcd - r8) * q8) + pos;
  const int ntx = N >> 8;
  const long bcol = (long)(wg % ntx) << 8;
  const long brow = (long)(wg / ntx) << 8;

  char* const ldsA0 = (char*)lds;
  char* const ldsB0 = (char*)lds + 65536;
  const int rowAoff = (wm * 64 + (lane & 15)) * 128;
  const int rowBoff = (wn * 32 + (lane & 15)) * 128;
  const int kA = (((lane >> 4) ^ (lane & 7)) << 4);

  f32x4 acc[2][4][2][2] = {};           // [ah][mf][bh][nf]
  const int KT = K >> 6;

  // prologue: stage tile 0 in FIFO order B0,B1,A0,A1 -> buf0
  stage_half(Bt, ldsB0,          bcol,       K, 0, wave, lane);
  stage_half(Bt, ldsB0 + 16384,  bcol + 128, K, 0, wave, lane);
  stage_half(A,  ldsA0,          brow,       K, 0, wave, lane);
  stage_half(A,  ldsA0 + 16384,  brow + 128, K, 0, wave, lane);
  VMCNT2;                               // B0,B1,A0 landed; A1 may be in flight
  __builtin_amdgcn_s_barrier();

  for (int t = 0; t < KT; ++t) {
    const int c = t & 1;
    char* const A_c = ldsA0 + c * 32768;
    char* const B_c = ldsB0 + c * 32768;
    char* const A_n = ldsA0 + (c ^ 1) * 32768;
    char* const B_n = ldsB0 + (c ^ 1) * 32768;
    const int tn = (t + 1 < KT) ? (t + 1) : t;      // clamp keeps FIFO uniform
    const long kbn = (long)tn << 7;
    short8 aF[4][2], aG[4][2], bF[2][2], bG[2][2];

    // p0: read aF,bF,bG (all fenced at entry); MFMA (0,0); stage B0(t+1)
    stage_half(Bt, B_n, bcol, K, kbn, wave, lane);
    READ_AF(aF, 0); READ_BF(bF, 0); READ_BF(bG, 1);
    MFMA_Q(0, aF, 0, bF);

    // p1: MFMA (0,1) [aF,bG kept, zero new reads]; stage B1(t+1); mid fence
    stage_half(Bt, B_n + 16384, bcol + 128, K, kbn, wave, lane);
    MFMA_Q(0, aF, 1, bG);
    VMCNT4;                             // own A1(t) landed
    __builtin_amdgcn_s_barrier();       // ALL waves' A1(t) landed

    // p2: read aG; MFMA (1,1) [bG kept]; stage A0(t+1)
    stage_half(A, A_n, brow, K, kbn, wave, lane);
    READ_AF(aG, 1);
    MFMA_Q(1, aG, 1, bG);

    // p3: MFMA (1,0) [aG,bF kept, zero new reads]; stage A1(t+1); tile fence
    stage_half(A, A_n + 16384, brow + 128, K, kbn, wave, lane);
    MFMA_Q(1, aG, 0, bF);
    VMCNT2;                             // own B0,B1,A0 (t+1) landed
    __builtin_amdgcn_s_barrier();       // ALL waves' B0,B1,A0 (t+1) landed
  }

  // epilogue
#pragma unroll
  for (int ah = 0; ah < 2; ++ah)
#pragma unroll
  for (int mf = 0; mf < 4; ++mf) {
    const long row0 = brow + ah * 128 + wm * 64 + mf * 16 + ((lane >> 4) << 2);
#pragma unroll
    for (int bh = 0; bh < 2; ++bh)
#pragma unroll
    for (int nf = 0; nf < 2; ++nf) {
      const long col = bcol + bh * 128 + wn * 32 + nf * 16 + (lane & 15);
#pragma unroll
      for (int j = 0; j < 4; ++j) {
        const long idx = (row0 + j) * N + col;
        const float v = acc[ah][mf][bh][nf][j];
        if constexpr (EPI == EPI_BF16) {
          reinterpret_cast<bf16*>(Cp)[idx] = __float2bfloat16(v);
        } else if constexpr (EPI == EPI_SCALE_F32) {
          reinterpret_cast<float*>(Cp)[idx] = v * scale;
        } else if constexpr (EPI == EPI_ENH) {
          reinterpret_cast<bf16*>(Cp)[idx] =
              __float2bfloat16(__bfloat162float(sel[idx]) + 0.1f * v);
        } else if constexpr (EPI == EPI_GELU_BIAS) {
          const float tt = v + bias[col];
          reinterpret_cast<bf16*>(Cp)[idx] =
              __float2bfloat16(0.5f * tt * (1.0f + erff(tt * 0.7071067811865475f)));
        } else if constexpr (EPI == EPI_BIAS_BF16) {
          reinterpret_cast<bf16*>(Cp)[idx] = __float2bfloat16(v + bias[col]);
        } else {
          reinterpret_cast<float*>(Cp)[idx] = v + bias[col];
        }
      }
    }
  }
}

// ---------------------------------------------------------------------------
// 128x128 NT GEMM (4 waves) — kept for M=512 GEMMs (q, scores, final)
// ---------------------------------------------------------------------------
template<int EPI>
__global__ __launch_bounds__(256)
void gemm_nt(const bf16* __restrict__ A, const bf16* __restrict__ Bt,
             void* __restrict__ Cp, const bf16* __restrict__ sel,
             const float* __restrict__ bias, float scale,
             int M, int N, int K)
{
  __shared__ bf16 As[128 * 64];
  __shared__ bf16 Bs[128 * 64];
  const int tid  = threadIdx.x;
  const int lane = tid & 63;
  const int wave = tid >> 6;
  const int wm = wave >> 1, wn = wave & 1;
  const long brow = (long)blockIdx.y * 128;
  const long bcol = (long)blockIdx.x * 128;

  f32x4 acc[4][4] = {};

  for (int k0 = 0; k0 < K; k0 += 64) {
    __syncthreads();
#pragma unroll
    for (int i = 0; i < 4; ++i) {
      const int s  = i * 256 + tid;
      const int r  = s >> 3;
      const int cs = s & 7;
      const int col = ((cs ^ (r & 7)) << 3);
      *reinterpret_cast<short8*>(&As[s << 3]) =
          *reinterpret_cast<const short8*>(&A[(brow + r) * K + k0 + col]);
      *reinterpret_cast<short8*>(&Bs[s << 3]) =
          *reinterpret_cast<const short8*>(&Bt[(bcol + r) * K + k0 + col]);
    }
    __syncthreads();
#pragma unroll
    for (int kk = 0; kk < 2; ++kk) {
      short8 af[4], bq[4];
      const int cc = (kk << 2) + (lane >> 4);
#pragma unroll
      for (int m = 0; m < 4; ++m) {
        const int r = wm * 64 + m * 16 + (lane & 15);
        af[m] = *reinterpret_cast<const short8*>(&As[((r << 3) + (cc ^ (r & 7))) << 3]);
      }
#pragma unroll
      for (int n = 0; n < 4; ++n) {
        const int r = wn * 64 + n * 16 + (lane & 15);
        bq[n] = *reinterpret_cast<const short8*>(&Bs[((r << 3) + (cc ^ (r & 7))) << 3]);
      }
#pragma unroll
      for (int m = 0; m < 4; ++m)
#pragma unroll
        for (int n = 0; n < 4; ++n)
          acc[m][n] = __builtin_amdgcn_mfma_f32_16x16x32_bf16(af[m], bq[n], acc[m][n], 0, 0, 0);
    }
  }

#pragma unroll
  for (int m = 0; m < 4; ++m) {
    const long row0 = brow + wm * 64 + m * 16 + ((lane >> 4) << 2);
#pragma unroll
    for (int n = 0; n < 4; ++n) {
      const long col = bcol + wn * 64 + n * 16 + (lane & 15);
#pragma unroll
      for (int j = 0; j < 4; ++j) {
        const long idx = (row0 + j) * N + col;
        const float v = acc[m][n][j];
        if constexpr (EPI == EPI_BF16) {
          reinterpret_cast<bf16*>(Cp)[idx] = __float2bfloat16(v);
        } else if constexpr (EPI == EPI_SCALE_F32) {
          reinterpret_cast<float*>(Cp)[idx] = v * scale;
        } else if constexpr (EPI == EPI_ENH) {
          reinterpret_cast<bf16*>(Cp)[idx] =
              __float2bfloat16(__bfloat162float(sel[idx]) + 0.1f * v);
        } else if constexpr (EPI == EPI_GELU_BIAS) {
          const float t = v + bias[col];
          reinterpret_cast<bf16*>(Cp)[idx] =
              __float2bfloat16(0.5f * t * (1.0f + erff(t * 0.7071067811865475f)));
        } else if constexpr (EPI == EPI_BIAS_BF16) {
          reinterpret_cast<bf16*>(Cp)[idx] = __float2bfloat16(v + bias[col]);
        } else {
          reinterpret_cast<float*>(Cp)[idx] = v + bias[col];
        }
      }
    }
  }
}

// ---------------------------------------------------------------------------
__global__ __launch_bounds__(256)
void k_convert_bf16(const float* __restrict__ in, bf16* __restrict__ out, long n4)
{
  const long i = (long)blockIdx.x * 256 + threadIdx.x;
  if (i >= n4) return;
  const f32x4 v = *reinterpret_cast<const f32x4*>(&in[i * 4]);
  bf16 o[4] __attribute__((aligned(8)));
#pragma unroll
  for (int j = 0; j < 4; ++j) o[j] = __float2bfloat16(v[j]);
  *reinterpret_cast<uint2v*>(&out[i * 4]) = *reinterpret_cast<uint2v*>(o);
}

__global__ __launch_bounds__(256)
void k_transpose_bf16(const float* __restrict__ in, bf16* __restrict__ out, int R, int C)
{
  __shared__ float t[64][65];
  const int bc = blockIdx.x << 6;
  const int br = blockIdx.y << 6;
  for (int i = threadIdx.x; i < 4096; i += 256) {
    const int r = i >> 6, c = i & 63;
    t[r][c] = in[(long)(br + r) * C + (bc + c)];
  }
  __syncthreads();
  for (int i = threadIdx.x; i < 4096; i += 256) {
    const int r = i >> 6, c = i & 63;
    out[(long)(bc + r) * R + (br + c)] = __float2bfloat16(t[c][r]);
  }
}

__global__ __launch_bounds__(256)
void k_gather_bf16(const float* __restrict__ src, const int* __restrict__ map,
                   bf16* __restrict__ dst, int cols)
{
  const long i = (long)blockIdx.x * 256 + threadIdx.x;
  const int cpr = cols >> 2;
  const int row = (int)(i / cpr);
  const int c4  = (int)(i % cpr) << 2;
  const f32x4 v = *reinterpret_cast<const f32x4*>(&src[(long)map[row] * cols + c4]);
  bf16 o[4] __attribute__((aligned(8)));
#pragma unroll
  for (int j = 0; j < 4; ++j) o[j] = __float2bfloat16(v[j]);
  *reinterpret_cast<uint2v*>(&dst[(long)row * cols + c4]) = *reinterpret_cast<uint2v*>(o);
}

__global__ __launch_bounds__(256)
void k_softmax_topk(const float* __restrict__ scores, int* __restrict__ tki,
                    float* __restrict__ tkw)
{
  const int b = blockIdx.x;
  const float* row = scores + (long)b * Nn;
  const int tid = threadIdx.x;
  __shared__ float red[8];
  __shared__ float cv[2048];
  __shared__ int   ci[2048];

  float mx = -INFINITY;
  for (int i = tid; i < Nn; i += 256) mx = fmaxf(mx, row[i]);
#pragma unroll
  for (int o = 32; o; o >>= 1) mx = fmaxf(mx, __shfl_down(mx, o));
  if ((tid & 63) == 0) red[tid >> 6] = mx;
  __syncthreads();
  mx = fmaxf(fmaxf(red[0], red[1]), fmaxf(red[2], red[3]));

  float tv[8]; int ti[8];
#pragma unroll
  for (int j = 0; j < 8; ++j) { tv[j] = -INFINITY; ti[j] = 0x7fffffff; }
  float sum = 0.f;
  for (int i = tid; i < Nn; i += 256) {
    const float v = row[i];
    sum += expf(v - mx);
    if (v > tv[7]) {
      tv[7] = v; ti[7] = i;
#pragma unroll
      for (int j = 7; j > 0; --j) {
        const bool sw = (tv[j] > tv[j-1]) || (tv[j] == tv[j-1] && ti[j] < ti[j-1]);
        if (sw) {
          const float fv = tv[j]; tv[j] = tv[j-1]; tv[j-1] = fv;
          const int   iv = ti[j]; ti[j] = ti[j-1]; ti[j-1] = iv;
        }
      }
    }
  }
  float s2 = sum;
#pragma unroll
  for (int o = 32; o; o >>= 1) s2 += __shfl_down(s2, o);
  if ((tid & 63) == 0) red[4 + (tid >> 6)] = s2;

#pragma unroll
  for (int j = 0; j < 8; ++j) { cv[tid * 8 + j] = tv[j]; ci[tid * 8 + j] = ti[j]; }
  __syncthreads();
  const float denom = red[4] + red[5] + red[6] + red[7];

  if (tid < 64) {
    for (int p = 0; p < 8; ++p) {
      float bv = -INFINITY; int bi = 0x7fffffff;
      for (int q = 0; q < 32; ++q) {
        const int slot = tid + (q << 6);
        const float v = cv[slot]; const int id = ci[slot];
        if (v > bv || (v == bv && id < bi)) { bv = v; bi = id; }
      }
#pragma unroll
      for (int o = 32; o; o >>= 1) {
        const float ov = __shfl_xor(bv, o);
        const int   oi = __shfl_xor(bi, o);
        if (ov > bv || (ov == bv && oi < bi)) { bv = ov; bi = oi; }
      }
      if (tid == 0) { tki[b * 8 + p] = bi; tkw[b * 8 + p] = expf(bv - mx) / denom; }
      for (int q = 0; q < 32; ++q) {
        const int slot = tid + (q << 6);
        if (ci[slot] == bi) cv[slot] = -INFINITY;
      }
    }
  }
}

__global__ __launch_bounds__(256)
void k_agg_xa(const float* __restrict__ x, const bf16* __restrict__ hout,
              const float* __restrict__ tkw, bf16* __restrict__ xa)
{
  const long i = (long)blockIdx.x * 256 + threadIdx.x;
  const int b = (int)(i >> 12);
  const int d = (int)(i & 4095);
  float a = x[i];
#pragma unroll
  for (int k = 0; k < 8; ++k)
    a += tkw[b * 8 + k] * __bfloat162float(hout[(((long)b * 8 + k) << 12) + d]);
  xa[i] = __float2bfloat16(a);
}

__global__ __launch_bounds__(256)
void k_conf(const float* __restrict__ fin, const float* __restrict__ Wc,
            float* __restrict__ conf)
{
  const int b = blockIdx.x;
  float s = 0.f;
  for (int d = threadIdx.x; d < Dd; d += 256)
    s += fin[(long)b * Dd + d] * Wc[d];
#pragma unroll
  for (int o = 32; o; o >>= 1) s += __shfl_down(s, o);
  __shared__ float r4[4];
  if ((threadIdx.x & 63) == 0) r4[threadIdx.x >> 6] = s;
  __syncthreads();
  if (threadIdx.x == 0) {
    const float t = r4[0] + r4[1] + r4[2] + r4[3];
    conf[b] = 1.f / (1.f + expf(-t));
  }
}

// ---------------------------------------------------------------------------
template<int EPI>
static inline void launch_gemm(const bf16* A, const bf16* Bt, void* C,
                               const bf16* sel, const float* bias, float scale,
                               int M, int N, int K, hipStream_t st)
{
  gemm_nt<EPI><<<dim3(N / 128, M / 128), 256, 0, st>>>(A, Bt, C, sel, bias, scale, M, N, K);
}

template<int EPI>
static inline void launch_gemm256(const bf16* A, const bf16* Bt, void* C,
                                  const bf16* sel, const float* bias,
                                  int M, int N, int K, hipStream_t st)
{
  gemm_nt_256<EPI><<<dim3((M >> 8) * (N >> 8)), 512, 0, st>>>(A, Bt, C, sel, bias, 1.f, M, N, K);
}

extern "C" void kernel_launch(void* const* d_in, const int* in_sizes, int n_in,
                              void* d_out, int out_size, void* d_ws, size_t ws_size,
                              hipStream_t stream)
{
  const float* x   = (const float*)d_in[0];
  const float* ne  = (const float*)d_in[1];
  const float* adj = (const float*)d_in[2];
  const float* Wq  = (const float*)d_in[3];
  const float* Wk  = (const float*)d_in[4];
  const float* W1  = (const float*)d_in[5];
  const float* b1  = (const float*)d_in[6];
  const float* W2  = (const float*)d_in[7];
  const float* b2  = (const float*)d_in[8];
  const float* Wc  = (const float*)d_in[9];
  const float* Wo  = (const float*)d_in[10];
  const float* bo  = (const float*)d_in[11];
  float* out = (float*)d_out;

  char* ws = (char*)d_ws;
  bf16*  slot0  = (bf16*)(ws);                 // 64MB: ne_bf16 -> adjG -> hout
  bf16*  slot1  = (bf16*)(ws + 67108864);      // 64MB: keys -> neT -> enh
  bf16*  slotW  = (bf16*)(ws + 134217728);     // 32MB: transposed weight slot
  bf16*  slot3  = (bf16*)(ws + 167772160);     // 32MB: sel -> hmid
  bf16*  slot4  = (bf16*)(ws + 201326592);     // 32MB: msg
  bf16*  xbf    = (bf16*)(ws + 234881024);     // 4MB
  bf16*  qbf    = (bf16*)(ws + 239075328);     // 4MB
  float* scores = (float*)(ws + 243269632);    // 16MB
  int*   tki    = (int*)(ws + 260046848);
  float* tkw    = (float*)(ws + 260063232);
  bf16*  xa     = (bf16*)(ws + 260079616);     // 4MB

  const long neN4 = (long)Nn * Dd / 4;
  const long xN4  = (long)Bsz * Dd / 4;

  // 1. node_emb -> bf16
  k_convert_bf16<<<(int)(neN4 / 256), 256, 0, stream>>>(ne, slot0, neN4);
  // 2. Wk^T
  k_transpose_bf16<<<dim3(64, 64), 256, 0, stream>>>(Wk, slotW, Dd, Dd);
  // 3. keys = ne @ Wk
  launch_gemm256<EPI_BF16>(slot0, slotW, slot1, nullptr, nullptr, Nn, Dd, Dd, stream);
  // 4. x -> bf16
  k_convert_bf16<<<(int)(xN4 / 256), 256, 0, stream>>>(x, xbf, xN4);
  // 5. Wq^T
  k_transpose_bf16<<<dim3(64, 64), 256, 0, stream>>>(Wq, slotW, Dd, Dd);
  // 6. q = x @ Wq  (M=512 -> 128^2 kernel)
  launch_gemm<EPI_BF16>(xbf, slotW, qbf, nullptr, nullptr, 1.f, Bsz, Dd, Dd, stream);
  // 7. scores = (q @ keys^T) / 64
  launch_gemm<EPI_SCALE_F32>(qbf, slot1, scores, nullptr, nullptr, 1.f / 64.f,
                             Bsz, Nn, Dd, stream);
  // 8. softmax stats + top-8
  k_softmax_topk<<<Bsz, 256, 0, stream>>>(scores, tki, tkw);
  // 9. sel = node_emb[topk] (bf16)
  k_gather_bf16<<<(int)((long)4096 * Dd / 4 / 256), 256, 0, stream>>>(ne, tki, slot3, Dd);
  // 10. adjG = adj[topk] (bf16)
  k_gather_bf16<<<(int)((long)4096 * Nn / 4 / 256), 256, 0, stream>>>(adj, tki, slot0, Nn);
  // 11. node_emb^T (keys dead)
  k_transpose_bf16<<<dim3(Dd / 64, Nn / 64), 256, 0, stream>>>(ne, slot1, Nn, Dd);
  // 12. msg = adjG @ node_emb
  launch_gemm256<EPI_BF16>(slot0, slot1, slot4, nullptr, nullptr, 4096, Dd, Nn, stream);
  // 13. enh = sel + 0.1 * (msg @ sel^T)   (neT dead -> enh in slot1)
  launch_gemm256<EPI_ENH>(slot4, slot3, slot1, slot3, nullptr, 4096, Dd, Dd, stream);
  // 14. W1^T
  k_transpose_bf16<<<dim3(Hh / 64, Dd / 64), 256, 0, stream>>>(W1, slotW, Dd, Hh);
  // 15. hmid = gelu(enh @ W1 + b1)   (sel dead -> hmid in slot3)
  launch_gemm256<EPI_GELU_BIAS>(slot1, slotW, slot3, nullptr, b1, 4096, Hh, Dd, stream);
  // 16. W2^T
  k_transpose_bf16<<<dim3(Dd / 64, Hh / 64), 256, 0, stream>>>(W2, slotW, Hh, Dd);
  // 17. hout = hmid @ W2 + b2   (adjG dead -> hout in slot0)
  launch_gemm256<EPI_BIAS_BF16>(slot3, slotW, slot0, nullptr, b2, 4096, Dd, Hh, stream);
  // 18. xa = bf16(x + sum_k w*hout)
  k_agg_xa<<<(int)((long)Bsz * Dd / 256), 256, 0, stream>>>(x, slot0, tkw, xa);
  // 19. Wo^T
  k_transpose_bf16<<<dim3(64, 64), 256, 0, stream>>>(Wo, slotW, Dd, Dd);
  // 20. final = xa @ Wo + bo -> d_out (f32)
  launch_gemm<EPI_BIAS_F32>(xa, slotW, out, nullptr, bo, 1.f, Bsz, Dd, Dd, stream);
  // 21. conf = sigmoid(final @ Wc)
  k_conf<<<Bsz, 256, 0, stream>>>(out, Wc, out + (long)Bsz * Dd);
}